// Round 5
// baseline (234.086 us; speedup 1.0000x reference)
//
#include <hip/hip_runtime.h>

typedef __bf16 bf16_t;
typedef __bf16 bf16x8 __attribute__((ext_vector_type(8)));
typedef __bf16 bf16x4 __attribute__((ext_vector_type(4)));
typedef float  floatx4 __attribute__((ext_vector_type(4)));

__device__ __forceinline__ void gload_lds16(const bf16_t* g, bf16_t* l) {
    __builtin_amdgcn_global_load_lds(
        (const __attribute__((address_space(1))) void*)g,
        (__attribute__((address_space(3))) void*)l,
        16, 0, 0);
}

// ---------------------------------------------------------------------------
// 256xBN 8-phase counted-vmcnt GEMM (C = A * B^T, NT, row-major, K-contig),
// with REGISTER-PREFETCH: each phase ds-reads the NEXT phase's fragments
// while the CURRENT phase's MFMA cluster runs. Rationale (round-4 PMC): the
// LDS unit is per-CU; 48 ds_read_b128/phase (~576 cyc CU-LDS) serialized
// against ~620 cyc of MFMA when both sit between the same barriers ->
// ~30% MfmaUtil. Prefetch moves the reads under the MFMA cluster.
// Safety: reads shift 1 phase earlier => stage-overwrite gaps grow (>=1
// barrier); vmcnt ledger unchanged; ph4/ph8 prefetches of the next buffer
// sit AFTER the covering vmcnt+barrier. Tail ph8 prefetch reads stale-but-
// landed data, never consumed.
// 512 threads = 8 waves (2M x 4N); wave tile 128 x (BN/4); BK=64.
// BN=256: LDS 128 KiB, vmcnt(6).  BN=128: LDS 96 KiB, vmcnt(4).
// 1 block/CU => grids exactly 256 blocks (round-1 lesson).
// MAP (round-4 win: FETCH 87->35 MB): XCD = flat_id % 8.
//  MAP 0: natural. MAP 1: 8x8x4 grids. MAP 2: 4x64 grid.
// MODE 1: plain bf16 C store                       (V^T direct, BN=128)
// MODE 2: bf16 C = exp(acc*scale) + atomic rowsums (Sc, BN=256)
// MODE 3: float C = acc / rowsums[row]             (PV, BN=128)
// MODE 5: split store: bn<1024 -> C (Q), else C2 (K)          (BN=256)
// ---------------------------------------------------------------------------
template <int MODE, int BN, int MAP, typename OutT>
__global__ __launch_bounds__(512, 2) void gemm8p(
    const bf16_t* __restrict__ A, int lda, size_t batchA,
    const bf16_t* __restrict__ B, int ldb, size_t batchB,
    OutT* __restrict__ C, int ldc, size_t batchC,
    bf16_t* __restrict__ C2,
    float* __restrict__ rowsums, int batchR,
    int K, float scale)
{
    extern __shared__ __align__(16) bf16_t smem[];

    constexpr int NJ   = BN / 64;        // B-fragments per wave (4 or 2)
    constexpr int WCB  = BN / 4;         // wave col base stride (64 or 32)
    constexpr int BGL  = BN / 128;       // gloads per B-region (2 or 1)
    constexpr int AREG = 8192;           // A region elems (256 rows x 32 k)
    constexpr int BREG = BN * 32;        // B region elems (BN rows x 32 k)
    constexpr int BOFF = 2 * AREG;
    constexpr int BUFS = BOFF + 2 * BREG;  // per-dbuf elems
    constexpr int VM   = 2 + 2 * BGL;    // counted vmcnt (6 or 4)

    int bxL, byL, bzL;
    if constexpr (MAP == 1) {
        const int h = blockIdx.x, k = h & 7, s = h >> 3;
        bzL = k >> 1; bxL = ((k & 1) << 2) | (s & 3); byL = s >> 2;
    } else if constexpr (MAP == 2) {
        const int h = blockIdx.x, k = h & 7, s = h >> 3;
        bzL = 0; bxL = s >> 3; byL = (k << 3) | (s & 7);
    } else {
        bxL = blockIdx.x; byL = blockIdx.y; bzL = blockIdx.z;
    }

    A += (size_t)bzL * batchA;
    B += (size_t)bzL * batchB;

    const int tid  = threadIdx.x;
    const int wid  = tid >> 6;
    const int lane = tid & 63;
    const int wr   = wid >> 2;   // 0..1  (M wave row)
    const int wc   = wid & 3;    // 0..3  (N wave col)
    const int lr   = lane & 15;

    const int bm = bxL * 256;
    const int bn = byL * BN;

    const bf16_t* At = A + (size_t)bm * lda;
    const bf16_t* Bt = B + (size_t)bn * ldb;

    // staging: region rows are 64 B (4 x 16 B chunks); LDS dest linear,
    // source chunk pre-swizzled: slot s of row r holds chunk s^((r>>1)&3).
    const int    c8 = (((lane & 3) ^ ((lane >> 3) & 3)) << 3);
    const size_t ga = (size_t)(wid * 16 + (lane >> 2)) * lda + c8;
    const size_t gb = (size_t)(wid * 16 + (lane >> 2)) * ldb + c8;

    // fragment reads: row r, k-chunk q=lane>>4 lives at slot q^((lr>>1)&3)
    const int slotoff = (((lane >> 4) ^ ((lr >> 1) & 3)) << 3);

    const int NT = K >> 6;            // 64-deep K tiles (even)

    floatx4 acc[8][NJ] = {};
    bf16x8 af[2][4], bq[2][NJ];       // double-buffered fragment registers

#define RBASE(sbuf, sreg)                                                     \
    ((sbuf) * BUFS + ((sreg) < 2 ? (sreg) * AREG : BOFF + ((sreg) - 2) * BREG))

#define STAGE(sbuf, sreg, tile) do {                                          \
    bf16_t* _l = smem + RBASE(sbuf, sreg) + (wid << 9);                       \
    const size_t _k = (size_t)(tile) * 64 + ((sreg) & 1) * 32;                \
    if ((sreg) >= 2) {                                                        \
        gload_lds16(Bt + _k + gb, _l);                                        \
        if (BGL == 2)                                                         \
            gload_lds16(Bt + _k + gb + (size_t)128 * ldb, _l + 4096);         \
    } else {                                                                  \
        gload_lds16(At + _k + ga, _l);                                        \
        gload_lds16(At + _k + ga + (size_t)128 * lda, _l + 4096);             \
    }                                                                         \
} while (0)

#define LDA_FRAG(buf, kk, row)                                                \
    (*(const bf16x8*)&smem[(buf) * BUFS + (kk) * AREG + ((row) << 5) + slotoff])
#define LDB_FRAG(buf, kk, row)                                                \
    (*(const bf16x8*)&smem[(buf) * BUFS + BOFF + (kk) * BREG + ((row) << 5) + slotoff])

// One phase. cm: current mh quadrant (acc index). CA/CB: reg sets consumed
// by this phase's MFMA. Prefetch (nb,nk,nm) into af[CA^1] (+ bq[CB^1] if
// NRDB) AFTER bar#1, so the LDS reads drain under the MFMA cluster; their
// consumer is the NEXT phase's MFMA (lgkmcnt satisfied by then).
#define PHASE(cm, CA, CB, nb, nk, nm, NRDB, sbuf, sreg, stile, DOVM) do {     \
    STAGE(sbuf, sreg, stile);                                                 \
    if (DOVM) {                                                               \
        if constexpr (VM == 6) asm volatile("s_waitcnt vmcnt(6)" ::: "memory");\
        else                   asm volatile("s_waitcnt vmcnt(4)" ::: "memory");\
    }                                                                         \
    __builtin_amdgcn_s_barrier();                                             \
    if (NRDB) {                                                               \
        _Pragma("unroll")                                                     \
        for (int j = 0; j < NJ; ++j)                                          \
            bq[CB ^ 1][j] = LDB_FRAG(nb, nk, wc * WCB + j * 16 + lr);         \
    }                                                                         \
    _Pragma("unroll")                                                         \
    for (int i = 0; i < 4; ++i)                                               \
        af[CA ^ 1][i] = LDA_FRAG(nb, nk, wr * 128 + (nm) * 64 + i * 16 + lr); \
    __builtin_amdgcn_s_setprio(1);                                            \
    _Pragma("unroll")                                                         \
    for (int i = 0; i < 4; ++i) {                                             \
        _Pragma("unroll")                                                     \
        for (int j = 0; j < NJ; ++j)                                          \
            acc[(cm) * 4 + i][j] = __builtin_amdgcn_mfma_f32_16x16x32_bf16(   \
                bq[CB][j], af[CA][i], acc[(cm) * 4 + i][j], 0, 0, 0);         \
    }                                                                         \
    __builtin_amdgcn_s_setprio(0);                                            \
    __builtin_amdgcn_s_barrier();                                             \
} while (0)

    // Prologue: buf0 fully + buf1 {Bk0,Ak0,Bk1}; vmcnt(VM) leaves exactly
    // buf1's three regions outstanding => buf0 landed. Then preload ph1's
    // fragments (buf0,kk0,mh0) into reg set 0.
    STAGE(0, 2, 0); STAGE(0, 0, 0); STAGE(0, 3, 0); STAGE(0, 1, 0);
    STAGE(1, 2, 1); STAGE(1, 0, 1); STAGE(1, 3, 1);
    if constexpr (VM == 6) asm volatile("s_waitcnt vmcnt(6)" ::: "memory");
    else                   asm volatile("s_waitcnt vmcnt(4)" ::: "memory");
    __builtin_amdgcn_s_barrier();
    #pragma unroll
    for (int j = 0; j < NJ; ++j)
        bq[0][j] = LDB_FRAG(0, 0, wc * WCB + j * 16 + lr);
    #pragma unroll
    for (int i = 0; i < 4; ++i)
        af[0][i] = LDA_FRAG(0, 0, wr * 128 + i * 16 + lr);

    for (int kt = 0; kt < NT; kt += 2) {
        int t1 = kt + 1;
        int t2 = kt + 2; if (t2 >= NT) t2 -= NT;   // tail wrap: redundant
        int t3 = kt + 3; if (t3 >= NT) t3 -= NT;   // stages, harmless
        //    cm CA CB  next     NRDB  stage      vm
        PHASE(0, 0, 0,  0, 0, 1, 0,    1, 1, t1,  0);
        PHASE(1, 1, 0,  0, 1, 0, 1,    0, 2, t2,  0);
        PHASE(0, 0, 1,  0, 1, 1, 0,    0, 0, t2,  0);
        PHASE(1, 1, 1,  1, 0, 0, 1,    0, 3, t2,  1);
        PHASE(0, 0, 0,  1, 0, 1, 0,    0, 1, t2,  0);
        PHASE(1, 1, 0,  1, 1, 0, 1,    1, 2, t3,  0);
        PHASE(0, 0, 1,  1, 1, 1, 0,    1, 0, t3,  0);
        PHASE(1, 1, 1,  0, 0, 0, 1,    1, 3, t3,  1);
    }
    asm volatile("s_waitcnt vmcnt(0)" ::: "memory");

#undef PHASE
#undef LDA_FRAG
#undef LDB_FRAG
#undef STAGE
#undef RBASE

    // D layout: m = lane&15 (arg1 = af), n = (lane>>4)*4 + reg (arg0 = bq)
    const int cfix = lane & 15;
    const int creg = (lane >> 4) << 2;

    if constexpr (MODE == 1) {
        OutT* Cz = C + (size_t)bzL * batchC;
        #pragma unroll
        for (int mi = 0; mi < 8; ++mi) {
            size_t row = (size_t)(bm + wr * 128 + mi * 16 + cfix);
            #pragma unroll
            for (int j = 0; j < NJ; ++j) {
                int col = bn + wc * WCB + j * 16 + creg;
                bf16x4 v;
                #pragma unroll
                for (int r = 0; r < 4; ++r) v[r] = (bf16_t)acc[mi][j][r];
                *(bf16x4*)&Cz[row * (size_t)ldc + col] = v;
            }
        }
    } else if constexpr (MODE == 5) {
        // fused QK split: cols [0,1024) -> C (Q), [1024,2048) -> C2 (K)
        bf16_t* dst = (bn < 1024) ? (bf16_t*)C : C2;
        const int cb = bn & 1023;
        #pragma unroll
        for (int mi = 0; mi < 8; ++mi) {
            size_t row = (size_t)(bm + wr * 128 + mi * 16 + cfix);
            #pragma unroll
            for (int j = 0; j < NJ; ++j) {
                int col = cb + wc * WCB + j * 16 + creg;
                bf16x4 v;
                #pragma unroll
                for (int r = 0; r < 4; ++r) v[r] = (bf16_t)acc[mi][j][r];
                *(bf16x4*)&dst[row * (size_t)ldc + col] = v;
            }
        }
    } else if constexpr (MODE == 2) {
        OutT* Cz = C + (size_t)bzL * batchC;
        float* sums = rowsums + (size_t)bzL * batchR;
        float rs[8] = {};
        #pragma unroll
        for (int mi = 0; mi < 8; ++mi) {
            size_t row = (size_t)(bm + wr * 128 + mi * 16 + cfix);
            #pragma unroll
            for (int j = 0; j < NJ; ++j) {
                int col = bn + wc * WCB + j * 16 + creg;
                bf16x4 v;
                #pragma unroll
                for (int r = 0; r < 4; ++r) {
                    v[r] = (bf16_t)__expf(acc[mi][j][r] * scale);
                    rs[mi] += (float)v[r];
                }
                *(bf16x4*)&Cz[row * (size_t)ldc + col] = v;
            }
        }
        #pragma unroll
        for (int mi = 0; mi < 8; ++mi) {
            rs[mi] += __shfl_xor(rs[mi], 16);
            rs[mi] += __shfl_xor(rs[mi], 32);
        }
        if (lane < 16) {
            #pragma unroll
            for (int mi = 0; mi < 8; ++mi)
                atomicAdd(&sums[bm + wr * 128 + mi * 16 + lane], rs[mi]);
        }
    } else {  // MODE == 3: PV with normalization
        OutT* Cz = C + (size_t)bzL * batchC;
        const float* sums = rowsums + (size_t)bzL * batchR;
        #pragma unroll
        for (int mi = 0; mi < 8; ++mi) {
            int rloc = bm + wr * 128 + mi * 16 + cfix;
            float rinv = 1.0f / sums[rloc];
            size_t row = (size_t)rloc;
            #pragma unroll
            for (int j = 0; j < NJ; ++j) {
                int col = bn + wc * WCB + j * 16 + creg;
                floatx4 v;
                #pragma unroll
                for (int r = 0; r < 4; ++r) v[r] = acc[mi][j][r] * rinv;
                *(floatx4*)&Cz[row * (size_t)ldc + col] = v;
            }
        }
    }
}

// fused fp32->bf16 conversion over X, Wq, Wk, Wv + zeroing of rowsums
__global__ __launch_bounds__(256) void cvt_all(
    const float* __restrict__ X, const float* __restrict__ Wq,
    const float* __restrict__ Wk, const float* __restrict__ Wv,
    bf16_t* __restrict__ Xb, bf16_t* __restrict__ Wqb,
    bf16_t* __restrict__ Wkb, bf16_t* __restrict__ Wvb,
    float* __restrict__ sums, int nsums,
    int nX4, int nW4)
{
    int i = blockIdx.x * blockDim.x + threadIdx.x;
    if (i < nsums) sums[i] = 0.f;    // d_ws is re-poisoned before every call
    const float* src; bf16_t* dst; int idx;
    if (i < nX4) { src = X; dst = Xb; idx = i; }
    else {
        int j = i - nX4;
        int w = j / nW4;
        idx = j - w * nW4;
        if (i >= nX4 + 3 * nW4) return;
        src = (w == 0) ? Wq : (w == 1) ? Wk : Wv;
        dst = (w == 0) ? Wqb : (w == 1) ? Wkb : Wvb;
    }
    float4 v = ((const float4*)src)[idx];
    bf16x4 o;
    o[0] = (bf16_t)v.x; o[1] = (bf16_t)v.y; o[2] = (bf16_t)v.z; o[3] = (bf16_t)v.w;
    *(bf16x4*)(dst + (size_t)idx * 4) = o;
}

extern "C" void kernel_launch(void* const* d_in, const int* in_sizes, int n_in,
                              void* d_out, int out_size, void* d_ws, size_t ws_size,
                              hipStream_t stream)
{
    (void)in_sizes; (void)n_in; (void)out_size; (void)ws_size;
    const float* X  = (const float*)d_in[0];
    const float* Wq = (const float*)d_in[1];
    const float* Wk = (const float*)d_in[2];
    const float* Wv = (const float*)d_in[3];
    float* out = (float*)d_out;

    const int Bb = 4, S = 2048, D = 1024;
    const int M = Bb * S;  // 8192

    char* ws = (char*)d_ws;
    size_t off = 0;
    auto carve = [&](size_t bytes) -> char* {
        char* p = ws + off;
        off += (bytes + 255) & ~(size_t)255;
        return p;
    };
    // Contiguity invariant: Wqb,Wkb adjacent (Wkb == Wqb + D*D): the fused
    // QK dispatch uses Wqb as a [2048][1024] B-matrix (Wq||Wk rows).
    bf16_t* Xb  = (bf16_t*)carve((size_t)M * D * 2);
    bf16_t* Wqb = (bf16_t*)carve((size_t)D * D * 2);
    bf16_t* Wkb = (bf16_t*)carve((size_t)D * D * 2);
    bf16_t* Wvb = (bf16_t*)carve((size_t)D * D * 2);
    bf16_t* Qb  = (bf16_t*)carve((size_t)M * D * 2);   // contiguous Q
    bf16_t* Kb  = (bf16_t*)carve((size_t)M * D * 2);   // contiguous K
    bf16_t* Vt  = (bf16_t*)carve((size_t)D * M * 2);   // V^T: D x M
    bf16_t* Sc  = (bf16_t*)carve((size_t)Bb * S * S * 2);
    float*  sums = (float*)carve((size_t)M * 4);

    static bool s_attr = false;
    if (!s_attr) {
        (void)hipFuncSetAttribute(
            reinterpret_cast<const void*>(&gemm8p<5, 256, 0, bf16_t>),
            hipFuncAttributeMaxDynamicSharedMemorySize, 131072);
        (void)hipFuncSetAttribute(
            reinterpret_cast<const void*>(&gemm8p<2, 256, 1, bf16_t>),
            hipFuncAttributeMaxDynamicSharedMemorySize, 131072);
        (void)hipFuncSetAttribute(
            reinterpret_cast<const void*>(&gemm8p<1, 128, 2, bf16_t>),
            hipFuncAttributeMaxDynamicSharedMemorySize, 98304);
        (void)hipFuncSetAttribute(
            reinterpret_cast<const void*>(&gemm8p<3, 128, 1, float>),
            hipFuncAttributeMaxDynamicSharedMemorySize, 98304);
        s_attr = true;
    }

    const int nX4 = M * D / 4, nW4 = D * D / 4;
    const int tot4 = nX4 + 3 * nW4;
    cvt_all<<<(tot4 + 255) / 256, 256, 0, stream>>>(
        X, Wq, Wk, Wv, Xb, Wqb, Wkb, Wvb, sums, M, nX4, nW4);

    // Fused QK: X * (Wq||Wk)^T, split-stored into contiguous Qb / Kb.
    // Grid 32x8 = 256 blocks, natural map (A panels already XCD-local).
    gemm8p<5, 256, 0, bf16_t><<<dim3(M / 256, (2 * D) / 256, 1), 512, 131072, stream>>>(
        Xb, D, 0, Wqb, D, 0, Qb, D, 0, Kb, nullptr, 0, D, 1.0f);

    // V^T direct: Vt[d][s] = sum_e Wv[d][e] X[s][e]. Logical grid 4x64,
    // launched 1D with MAP=2 (X panels single-XCD).
    gemm8p<1, 128, 2, bf16_t><<<dim3(256, 1, 1), 512, 98304, stream>>>(
        Wvb, D, 0, Xb, D, 0, Vt, M, 0, nullptr, nullptr, 0, D, 1.0f);

    // Sc = exp(Q K^T / 32) + row sums. Logical grid 8x8x4, MAP=1.
    gemm8p<2, 256, 1, bf16_t><<<dim3(256, 1, 1), 512, 131072, stream>>>(
        Qb, D, (size_t)S * D, Kb, D, (size_t)S * D, Sc, S, (size_t)S * S,
        nullptr, sums, S, D, 0.03125f);

    // out = (Sc V) / rowsum. Logical grid 8x8x4, MAP=1.
    gemm8p<3, 128, 1, float><<<dim3(256, 1, 1), 512, 98304, stream>>>(
        Sc, S, (size_t)S * S, Vt, M, (size_t)S, out, D, (size_t)S * D,
        nullptr, sums, S, S, 1.0f);
}

// Round 6
// 229.336 us; speedup vs baseline: 1.0207x; 1.0207x over previous
//
#include <hip/hip_runtime.h>

typedef __bf16 bf16_t;
typedef __bf16 bf16x8 __attribute__((ext_vector_type(8)));
typedef __bf16 bf16x4 __attribute__((ext_vector_type(4)));
typedef float  floatx4 __attribute__((ext_vector_type(4)));

__device__ __forceinline__ void gload_lds16(const bf16_t* g, bf16_t* l) {
    __builtin_amdgcn_global_load_lds(
        (const __attribute__((address_space(1))) void*)g,
        (__attribute__((address_space(3))) void*)l,
        16, 0, 0);
}

// ---------------------------------------------------------------------------
// 256xBN 8-phase counted-vmcnt GEMM (C = A * B^T, NT, row-major, K-contig),
// with REGISTER-PREFETCH + SCHED-PINNING.
// Round-5 lesson: s_barrier is IntrNoMem; without a scheduling fence the
// compiler sinks the prefetched ds_reads BELOW the MFMA cluster (MFMAs are
// register-only and cross memory clobbers), re-serializing the LDS pipe
// (~600 cyc/phase/CU) with the matrix pipe (~620 cyc) -> 1640 cyc phases,
// 785 TF on every dispatch. Fix: sched_barrier(0) right after bar#1 (reads
// can't hoist above the barrier - also closes a latent cross-wave race) and
// right before the MFMA cluster (reads can't sink below). Emits nothing.
// 512 threads = 8 waves (2M x 4N); wave tile 128 x (BN/4); BK=64.
// BN=256: LDS 128 KiB, vmcnt(6).  BN=128: LDS 96 KiB, vmcnt(4).
// 1 block/CU => grids exactly 256 blocks (round-1 lesson).
// MAP (round-4 win: FETCH 87->35 MB): XCD = flat_id % 8.
//  MAP 0: natural. MAP 1: 8x8x4 grids. MAP 2: 4x64 grid.
// MODE 1: plain bf16 C store                       (V^T direct, BN=128)
// MODE 2: bf16 C = exp(acc*scale) + atomic rowsums (Sc, BN=256)
// MODE 3: float C = acc / rowsums[row]             (PV, BN=128)
// MODE 5: split store: bn<1024 -> C (Q), else C2 (K)          (BN=256)
// ---------------------------------------------------------------------------
template <int MODE, int BN, int MAP, typename OutT>
__global__ __launch_bounds__(512, 2) void gemm8p(
    const bf16_t* __restrict__ A, int lda, size_t batchA,
    const bf16_t* __restrict__ B, int ldb, size_t batchB,
    OutT* __restrict__ C, int ldc, size_t batchC,
    bf16_t* __restrict__ C2,
    float* __restrict__ rowsums, int batchR,
    int K, float scale)
{
    extern __shared__ __align__(16) bf16_t smem[];

    constexpr int NJ   = BN / 64;        // B-fragments per wave (4 or 2)
    constexpr int WCB  = BN / 4;         // wave col base stride (64 or 32)
    constexpr int BGL  = BN / 128;       // gloads per B-region (2 or 1)
    constexpr int AREG = 8192;           // A region elems (256 rows x 32 k)
    constexpr int BREG = BN * 32;        // B region elems (BN rows x 32 k)
    constexpr int BOFF = 2 * AREG;
    constexpr int BUFS = BOFF + 2 * BREG;  // per-dbuf elems
    constexpr int VM   = 2 + 2 * BGL;    // counted vmcnt (6 or 4)

    int bxL, byL, bzL;
    if constexpr (MAP == 1) {
        const int h = blockIdx.x, k = h & 7, s = h >> 3;
        bzL = k >> 1; bxL = ((k & 1) << 2) | (s & 3); byL = s >> 2;
    } else if constexpr (MAP == 2) {
        const int h = blockIdx.x, k = h & 7, s = h >> 3;
        bzL = 0; bxL = s >> 3; byL = (k << 3) | (s & 7);
    } else {
        bxL = blockIdx.x; byL = blockIdx.y; bzL = blockIdx.z;
    }

    A += (size_t)bzL * batchA;
    B += (size_t)bzL * batchB;

    const int tid  = threadIdx.x;
    const int wid  = tid >> 6;
    const int lane = tid & 63;
    const int wr   = wid >> 2;   // 0..1  (M wave row)
    const int wc   = wid & 3;    // 0..3  (N wave col)
    const int lr   = lane & 15;

    const int bm = bxL * 256;
    const int bn = byL * BN;

    const bf16_t* At = A + (size_t)bm * lda;
    const bf16_t* Bt = B + (size_t)bn * ldb;

    // staging: region rows are 64 B (4 x 16 B chunks); LDS dest linear,
    // source chunk pre-swizzled: slot s of row r holds chunk s^((r>>1)&3).
    const int    c8 = (((lane & 3) ^ ((lane >> 3) & 3)) << 3);
    const size_t ga = (size_t)(wid * 16 + (lane >> 2)) * lda + c8;
    const size_t gb = (size_t)(wid * 16 + (lane >> 2)) * ldb + c8;

    // fragment reads: row r, k-chunk q=lane>>4 lives at slot q^((lr>>1)&3)
    const int slotoff = (((lane >> 4) ^ ((lr >> 1) & 3)) << 3);

    const int NT = K >> 6;            // 64-deep K tiles (even)

    floatx4 acc[8][NJ] = {};
    bf16x8 af[2][4], bq[2][NJ];       // double-buffered fragment registers

#define RBASE(sbuf, sreg)                                                     \
    ((sbuf) * BUFS + ((sreg) < 2 ? (sreg) * AREG : BOFF + ((sreg) - 2) * BREG))

#define STAGE(sbuf, sreg, tile) do {                                          \
    bf16_t* _l = smem + RBASE(sbuf, sreg) + (wid << 9);                       \
    const size_t _k = (size_t)(tile) * 64 + ((sreg) & 1) * 32;                \
    if ((sreg) >= 2) {                                                        \
        gload_lds16(Bt + _k + gb, _l);                                        \
        if (BGL == 2)                                                         \
            gload_lds16(Bt + _k + gb + (size_t)128 * ldb, _l + 4096);         \
    } else {                                                                  \
        gload_lds16(At + _k + ga, _l);                                        \
        gload_lds16(At + _k + ga + (size_t)128 * lda, _l + 4096);             \
    }                                                                         \
} while (0)

#define LDA_FRAG(buf, kk, row)                                                \
    (*(const bf16x8*)&smem[(buf) * BUFS + (kk) * AREG + ((row) << 5) + slotoff])
#define LDB_FRAG(buf, kk, row)                                                \
    (*(const bf16x8*)&smem[(buf) * BUFS + BOFF + (kk) * BREG + ((row) << 5) + slotoff])

// One phase. cm: current mh quadrant (acc index). CA/CB: reg sets consumed
// by this phase's MFMA. Prefetch (nb,nk,nm) into af[CA^1] (+ bq[CB^1] if
// NRDB) between the two sched_barrier(0) fences: reads are pinned after
// bar#1 and before the MFMA cluster, so the LDS pipe drains UNDER the
// matrix pipe; their consumer is the NEXT phase's MFMA (lgkmcnt counted
// by the compiler, satisfied by then).
#define PHASE(cm, CA, CB, nb, nk, nm, NRDB, sbuf, sreg, stile, DOVM) do {     \
    STAGE(sbuf, sreg, stile);                                                 \
    if (DOVM) {                                                               \
        if constexpr (VM == 6) asm volatile("s_waitcnt vmcnt(6)" ::: "memory");\
        else                   asm volatile("s_waitcnt vmcnt(4)" ::: "memory");\
    }                                                                         \
    __builtin_amdgcn_s_barrier();                                             \
    __builtin_amdgcn_sched_barrier(0);                                        \
    if (NRDB) {                                                               \
        _Pragma("unroll")                                                     \
        for (int j = 0; j < NJ; ++j)                                          \
            bq[CB ^ 1][j] = LDB_FRAG(nb, nk, wc * WCB + j * 16 + lr);         \
    }                                                                         \
    _Pragma("unroll")                                                         \
    for (int i = 0; i < 4; ++i)                                               \
        af[CA ^ 1][i] = LDA_FRAG(nb, nk, wr * 128 + (nm) * 64 + i * 16 + lr); \
    __builtin_amdgcn_sched_barrier(0);                                        \
    __builtin_amdgcn_s_setprio(1);                                            \
    _Pragma("unroll")                                                         \
    for (int i = 0; i < 4; ++i) {                                             \
        _Pragma("unroll")                                                     \
        for (int j = 0; j < NJ; ++j)                                          \
            acc[(cm) * 4 + i][j] = __builtin_amdgcn_mfma_f32_16x16x32_bf16(   \
                bq[CB][j], af[CA][i], acc[(cm) * 4 + i][j], 0, 0, 0);         \
    }                                                                         \
    __builtin_amdgcn_s_setprio(0);                                            \
    __builtin_amdgcn_s_barrier();                                             \
} while (0)

    // Prologue: buf0 fully + buf1 {Bk0,Ak0,Bk1}; vmcnt(VM) leaves exactly
    // buf1's three regions outstanding => buf0 landed. Then preload ph1's
    // fragments (buf0,kk0,mh0) into reg set 0.
    STAGE(0, 2, 0); STAGE(0, 0, 0); STAGE(0, 3, 0); STAGE(0, 1, 0);
    STAGE(1, 2, 1); STAGE(1, 0, 1); STAGE(1, 3, 1);
    if constexpr (VM == 6) asm volatile("s_waitcnt vmcnt(6)" ::: "memory");
    else                   asm volatile("s_waitcnt vmcnt(4)" ::: "memory");
    __builtin_amdgcn_s_barrier();
    __builtin_amdgcn_sched_barrier(0);
    #pragma unroll
    for (int j = 0; j < NJ; ++j)
        bq[0][j] = LDB_FRAG(0, 0, wc * WCB + j * 16 + lr);
    #pragma unroll
    for (int i = 0; i < 4; ++i)
        af[0][i] = LDA_FRAG(0, 0, wr * 128 + i * 16 + lr);
    __builtin_amdgcn_sched_barrier(0);

    for (int kt = 0; kt < NT; kt += 2) {
        int t1 = kt + 1;
        int t2 = kt + 2; if (t2 >= NT) t2 -= NT;   // tail wrap: redundant
        int t3 = kt + 3; if (t3 >= NT) t3 -= NT;   // stages, harmless
        //    cm CA CB  next     NRDB  stage      vm
        PHASE(0, 0, 0,  0, 0, 1, 0,    1, 1, t1,  0);
        PHASE(1, 1, 0,  0, 1, 0, 1,    0, 2, t2,  0);
        PHASE(0, 0, 1,  0, 1, 1, 0,    0, 0, t2,  0);
        PHASE(1, 1, 1,  1, 0, 0, 1,    0, 3, t2,  1);
        PHASE(0, 0, 0,  1, 0, 1, 0,    0, 1, t2,  0);
        PHASE(1, 1, 0,  1, 1, 0, 1,    1, 2, t3,  0);
        PHASE(0, 0, 1,  1, 1, 1, 0,    1, 0, t3,  0);
        PHASE(1, 1, 1,  0, 0, 0, 1,    1, 3, t3,  1);
    }
    asm volatile("s_waitcnt vmcnt(0)" ::: "memory");

#undef PHASE
#undef LDA_FRAG
#undef LDB_FRAG
#undef STAGE
#undef RBASE

    // D layout: m = lane&15 (arg1 = af), n = (lane>>4)*4 + reg (arg0 = bq)
    const int cfix = lane & 15;
    const int creg = (lane >> 4) << 2;

    if constexpr (MODE == 1) {
        OutT* Cz = C + (size_t)bzL * batchC;
        #pragma unroll
        for (int mi = 0; mi < 8; ++mi) {
            size_t row = (size_t)(bm + wr * 128 + mi * 16 + cfix);
            #pragma unroll
            for (int j = 0; j < NJ; ++j) {
                int col = bn + wc * WCB + j * 16 + creg;
                bf16x4 v;
                #pragma unroll
                for (int r = 0; r < 4; ++r) v[r] = (bf16_t)acc[mi][j][r];
                *(bf16x4*)&Cz[row * (size_t)ldc + col] = v;
            }
        }
    } else if constexpr (MODE == 5) {
        // fused QK split: cols [0,1024) -> C (Q), [1024,2048) -> C2 (K)
        bf16_t* dst = (bn < 1024) ? (bf16_t*)C : C2;
        const int cb = bn & 1023;
        #pragma unroll
        for (int mi = 0; mi < 8; ++mi) {
            size_t row = (size_t)(bm + wr * 128 + mi * 16 + cfix);
            #pragma unroll
            for (int j = 0; j < NJ; ++j) {
                int col = cb + wc * WCB + j * 16 + creg;
                bf16x4 v;
                #pragma unroll
                for (int r = 0; r < 4; ++r) v[r] = (bf16_t)acc[mi][j][r];
                *(bf16x4*)&dst[row * (size_t)ldc + col] = v;
            }
        }
    } else if constexpr (MODE == 2) {
        OutT* Cz = C + (size_t)bzL * batchC;
        float* sums = rowsums + (size_t)bzL * batchR;
        float rs[8] = {};
        #pragma unroll
        for (int mi = 0; mi < 8; ++mi) {
            size_t row = (size_t)(bm + wr * 128 + mi * 16 + cfix);
            #pragma unroll
            for (int j = 0; j < NJ; ++j) {
                int col = bn + wc * WCB + j * 16 + creg;
                bf16x4 v;
                #pragma unroll
                for (int r = 0; r < 4; ++r) {
                    v[r] = (bf16_t)__expf(acc[mi][j][r] * scale);
                    rs[mi] += (float)v[r];
                }
                *(bf16x4*)&Cz[row * (size_t)ldc + col] = v;
            }
        }
        #pragma unroll
        for (int mi = 0; mi < 8; ++mi) {
            rs[mi] += __shfl_xor(rs[mi], 16);
            rs[mi] += __shfl_xor(rs[mi], 32);
        }
        if (lane < 16) {
            #pragma unroll
            for (int mi = 0; mi < 8; ++mi)
                atomicAdd(&sums[bm + wr * 128 + mi * 16 + lane], rs[mi]);
        }
    } else {  // MODE == 3: PV with normalization
        OutT* Cz = C + (size_t)bzL * batchC;
        const float* sums = rowsums + (size_t)bzL * batchR;
        #pragma unroll
        for (int mi = 0; mi < 8; ++mi) {
            int rloc = bm + wr * 128 + mi * 16 + cfix;
            float rinv = 1.0f / sums[rloc];
            size_t row = (size_t)rloc;
            #pragma unroll
            for (int j = 0; j < NJ; ++j) {
                int col = bn + wc * WCB + j * 16 + creg;
                floatx4 v;
                #pragma unroll
                for (int r = 0; r < 4; ++r) v[r] = acc[mi][j][r] * rinv;
                *(floatx4*)&Cz[row * (size_t)ldc + col] = v;
            }
        }
    }
}

// fused fp32->bf16 conversion over X, Wq, Wk, Wv + zeroing of rowsums
__global__ __launch_bounds__(256) void cvt_all(
    const float* __restrict__ X, const float* __restrict__ Wq,
    const float* __restrict__ Wk, const float* __restrict__ Wv,
    bf16_t* __restrict__ Xb, bf16_t* __restrict__ Wqb,
    bf16_t* __restrict__ Wkb, bf16_t* __restrict__ Wvb,
    float* __restrict__ sums, int nsums,
    int nX4, int nW4)
{
    int i = blockIdx.x * blockDim.x + threadIdx.x;
    if (i < nsums) sums[i] = 0.f;    // d_ws is re-poisoned before every call
    const float* src; bf16_t* dst; int idx;
    if (i < nX4) { src = X; dst = Xb; idx = i; }
    else {
        int j = i - nX4;
        int w = j / nW4;
        idx = j - w * nW4;
        if (i >= nX4 + 3 * nW4) return;
        src = (w == 0) ? Wq : (w == 1) ? Wk : Wv;
        dst = (w == 0) ? Wqb : (w == 1) ? Wkb : Wvb;
    }
    float4 v = ((const float4*)src)[idx];
    bf16x4 o;
    o[0] = (bf16_t)v.x; o[1] = (bf16_t)v.y; o[2] = (bf16_t)v.z; o[3] = (bf16_t)v.w;
    *(bf16x4*)(dst + (size_t)idx * 4) = o;
}

extern "C" void kernel_launch(void* const* d_in, const int* in_sizes, int n_in,
                              void* d_out, int out_size, void* d_ws, size_t ws_size,
                              hipStream_t stream)
{
    (void)in_sizes; (void)n_in; (void)out_size; (void)ws_size;
    const float* X  = (const float*)d_in[0];
    const float* Wq = (const float*)d_in[1];
    const float* Wk = (const float*)d_in[2];
    const float* Wv = (const float*)d_in[3];
    float* out = (float*)d_out;

    const int Bb = 4, S = 2048, D = 1024;
    const int M = Bb * S;  // 8192

    char* ws = (char*)d_ws;
    size_t off = 0;
    auto carve = [&](size_t bytes) -> char* {
        char* p = ws + off;
        off += (bytes + 255) & ~(size_t)255;
        return p;
    };
    // Contiguity invariant: Wqb,Wkb adjacent (Wkb == Wqb + D*D): the fused
    // QK dispatch uses Wqb as a [2048][1024] B-matrix (Wq||Wk rows).
    bf16_t* Xb  = (bf16_t*)carve((size_t)M * D * 2);
    bf16_t* Wqb = (bf16_t*)carve((size_t)D * D * 2);
    bf16_t* Wkb = (bf16_t*)carve((size_t)D * D * 2);
    bf16_t* Wvb = (bf16_t*)carve((size_t)D * D * 2);
    bf16_t* Qb  = (bf16_t*)carve((size_t)M * D * 2);   // contiguous Q
    bf16_t* Kb  = (bf16_t*)carve((size_t)M * D * 2);   // contiguous K
    bf16_t* Vt  = (bf16_t*)carve((size_t)D * M * 2);   // V^T: D x M
    bf16_t* Sc  = (bf16_t*)carve((size_t)Bb * S * S * 2);
    float*  sums = (float*)carve((size_t)M * 4);

    static bool s_attr = false;
    if (!s_attr) {
        (void)hipFuncSetAttribute(
            reinterpret_cast<const void*>(&gemm8p<5, 256, 0, bf16_t>),
            hipFuncAttributeMaxDynamicSharedMemorySize, 131072);
        (void)hipFuncSetAttribute(
            reinterpret_cast<const void*>(&gemm8p<2, 256, 1, bf16_t>),
            hipFuncAttributeMaxDynamicSharedMemorySize, 131072);
        (void)hipFuncSetAttribute(
            reinterpret_cast<const void*>(&gemm8p<1, 128, 2, bf16_t>),
            hipFuncAttributeMaxDynamicSharedMemorySize, 98304);
        (void)hipFuncSetAttribute(
            reinterpret_cast<const void*>(&gemm8p<3, 128, 1, float>),
            hipFuncAttributeMaxDynamicSharedMemorySize, 98304);
        s_attr = true;
    }

    const int nX4 = M * D / 4, nW4 = D * D / 4;
    const int tot4 = nX4 + 3 * nW4;
    cvt_all<<<(tot4 + 255) / 256, 256, 0, stream>>>(
        X, Wq, Wk, Wv, Xb, Wqb, Wkb, Wvb, sums, M, nX4, nW4);

    // Fused QK: X * (Wq||Wk)^T, split-stored into contiguous Qb / Kb.
    // Grid 32x8 = 256 blocks, natural map (A panels already XCD-local).
    gemm8p<5, 256, 0, bf16_t><<<dim3(M / 256, (2 * D) / 256, 1), 512, 131072, stream>>>(
        Xb, D, 0, Wqb, D, 0, Qb, D, 0, Kb, nullptr, 0, D, 1.0f);

    // V^T direct: Vt[d][s] = sum_e Wv[d][e] X[s][e]. Logical grid 4x64,
    // launched 1D with MAP=2 (X panels single-XCD).
    gemm8p<1, 128, 2, bf16_t><<<dim3(256, 1, 1), 512, 98304, stream>>>(
        Wvb, D, 0, Xb, D, 0, Vt, M, 0, nullptr, nullptr, 0, D, 1.0f);

    // Sc = exp(Q K^T / 32) + row sums. Logical grid 8x8x4, MAP=1.
    gemm8p<2, 256, 1, bf16_t><<<dim3(256, 1, 1), 512, 131072, stream>>>(
        Qb, D, (size_t)S * D, Kb, D, (size_t)S * D, Sc, S, (size_t)S * S,
        nullptr, sums, S, D, 0.03125f);

    // out = (Sc V) / rowsum. Logical grid 8x8x4, MAP=1.
    gemm8p<3, 128, 1, float><<<dim3(256, 1, 1), 512, 98304, stream>>>(
        Sc, S, (size_t)S * S, Vt, M, (size_t)S, out, D, (size_t)S * D,
        nullptr, sums, S, S, 1.0f);
}